// Round 1
// baseline (120.416 us; speedup 1.0000x reference)
//
#include <hip/hip_runtime.h>
#include <math.h>

#define SS 8192
#define HH 2048
// W_att is (H, 2H) row-major, row stride 2*HH = 4096 floats.

// ws layout: v2 = ws[0 .. 2048)   (8 KB)
// scores live in d_out (8192 floats), softmax'd in place.

__global__ void zero_v2(float* __restrict__ v2) {
    int i = blockIdx.x * blockDim.x + threadIdx.x;
    if (i < HH) v2[i] = 0.0f;
}

// grid (8, 32), block 256. blockIdx.x picks 256 columns, blockIdx.y picks 64 rows.
// v2[col] += sum_j w[j] * W[j, HH + col]
__global__ void colsum_kernel(const float* __restrict__ W,
                              const float* __restrict__ w,
                              float* __restrict__ v2) {
    const int col  = blockIdx.x * 256 + threadIdx.x;   // 0..2047
    const int row0 = blockIdx.y * 64;
    const float* base = W + (size_t)row0 * (2 * HH) + HH + col;
    float acc = 0.0f;
#pragma unroll 8
    for (int j = 0; j < 64; ++j) {
        acc += w[row0 + j] * base[(size_t)j * (2 * HH)];
    }
    atomicAdd(&v2[col], acc);
}

// block 256 = 4 waves, one wave per row; grid 2048 -> 8192 rows.
__global__ void rowdot_kernel(const float* __restrict__ enc,
                              const float* __restrict__ v2,
                              float* __restrict__ scores) {
    const int wave = threadIdx.x >> 6;
    const int lane = threadIdx.x & 63;
    const int row  = blockIdx.x * 4 + wave;
    const float4* e = (const float4*)(enc + (size_t)row * HH);
    const float4* v = (const float4*)v2;
    float acc = 0.0f;
#pragma unroll
    for (int i = 0; i < 8; ++i) {         // 512 float4 per row / 64 lanes = 8
        float4 a = e[lane + i * 64];
        float4 b = v[lane + i * 64];
        acc += a.x * b.x + a.y * b.y + a.z * b.z + a.w * b.w;
    }
    for (int off = 32; off > 0; off >>= 1)
        acc += __shfl_down(acc, off);
    if (lane == 0) scores[row] = acc;
}

// single block, 1024 threads, 8 elements/thread; in-place softmax over d_out.
__global__ void softmax_kernel(float* __restrict__ buf) {
    __shared__ float red[16];
    const int tid  = threadIdx.x;
    const int lane = tid & 63;
    const int wid  = tid >> 6;             // 16 waves

    float vals[8];
    float m = -INFINITY;
#pragma unroll
    for (int i = 0; i < 8; ++i) {
        vals[i] = buf[tid + i * 1024];
        m = fmaxf(m, vals[i]);
    }
    for (int off = 1; off < 64; off <<= 1)
        m = fmaxf(m, __shfl_xor(m, off));
    if (lane == 0) red[wid] = m;
    __syncthreads();
    if (tid == 0) {
        float mm = red[0];
        for (int i = 1; i < 16; ++i) mm = fmaxf(mm, red[i]);
        red[0] = mm;
    }
    __syncthreads();
    m = red[0];

    float s = 0.0f;
#pragma unroll
    for (int i = 0; i < 8; ++i) {
        vals[i] = __expf(vals[i] - m);
        s += vals[i];
    }
    for (int off = 1; off < 64; off <<= 1)
        s += __shfl_xor(s, off);
    __syncthreads();                       // done reading red[0]
    if (lane == 0) red[wid] = s;
    __syncthreads();
    if (tid == 0) {
        float ss = 0.0f;
        for (int i = 0; i < 16; ++i) ss += red[i];
        red[0] = ss;
    }
    __syncthreads();
    const float inv = 1.0f / red[0];
#pragma unroll
    for (int i = 0; i < 8; ++i)
        buf[tid + i * 1024] = vals[i] * inv;
}

extern "C" void kernel_launch(void* const* d_in, const int* in_sizes, int n_in,
                              void* d_out, int out_size, void* d_ws, size_t ws_size,
                              hipStream_t stream) {
    const float* enc   = (const float*)d_in[0];  // (S,1,H) -> (S,H)
    // d_in[1] = hidden  : contributes only a constant score shift -> cancels in softmax
    const float* W_att = (const float*)d_in[2];  // (H, 2H)
    // d_in[3] = b_att   : constant shift -> cancels
    const float* w     = (const float*)d_in[4];  // (1, H)

    float* out = (float*)d_out;                  // 8192 floats; used as scores then softmax'd
    float* v2  = (float*)d_ws;                   // 2048 floats

    hipLaunchKernelGGL(zero_v2,        dim3(8),      dim3(256),  0, stream, v2);
    hipLaunchKernelGGL(colsum_kernel,  dim3(8, 32),  dim3(256),  0, stream, W_att, w, v2);
    hipLaunchKernelGGL(rowdot_kernel,  dim3(2048),   dim3(256),  0, stream, enc, v2, out);
    hipLaunchKernelGGL(softmax_kernel, dim3(1),      dim3(1024), 0, stream, out);
}